// Round 13
// baseline (247.374 us; speedup 1.0000x reference)
//
#include <hip/hip_runtime.h>
#include <hip/hip_bf16.h>

#define BROWS 32768
#define CDIM 1000
#define CPAD 1024
#define HDIM 128
// Bijective LDS word swizzle for the sort region (unchanged from v6).
#define SWZ(w) ((w) ^ ((((w) >> 5) & 7) << 2))

typedef __attribute__((ext_vector_type(8))) short short8;
typedef __attribute__((ext_vector_type(4))) float f32x4;

__device__ inline unsigned short f2bf(float x) {
    unsigned int b = __float_as_uint(x);
    unsigned int r = (b + 0x7FFFu + ((b >> 16) & 1u)) >> 16;  // RNE
    return (unsigned short)r;
}
__device__ inline float bf2f(unsigned short u) {
    return __uint_as_float(((unsigned int)u) << 16);
}

// ---------------- prep: transpose weights to [N][K] bf16, zero-padded ----------------
__global__ __launch_bounds__(256) void k_prep(const float* __restrict__ W1,
                                              const float* __restrict__ W2,
                                              const float* __restrict__ W3,
                                              unsigned short* __restrict__ W1t,
                                              unsigned short* __restrict__ W2t,
                                              unsigned short* __restrict__ W3t) {
    const int idx = blockIdx.x * 256 + threadIdx.x;  // [0, 131072)
    {   // W1t[n][k], n<128, k<1024 ; W1 is [1000][128]
        const int n = idx >> 10, k = idx & 1023;
        W1t[idx] = (k < CDIM) ? f2bf(W1[(size_t)k * HDIM + n]) : (unsigned short)0;
    }
    {   // W3t[n][k], n<1024, k<128 ; W3 is [128][1000]
        const int n = idx >> 7, k = idx & 127;
        W3t[idx] = (n < CDIM) ? f2bf(W3[(size_t)k * CDIM + n]) : (unsigned short)0;
    }
    if (idx < 16384) {  // W2t[n][k], 128x128 ; W2 is [128][128]
        const int n = idx >> 7, k = idx & 127;
        W2t[idx] = f2bf(W2[(size_t)k * HDIM + n]);
    }
}

// ---------------- fully fused: softmax -> MLP (3 MFMA GEMMs) -> sort -> finish --------
// One block = 16 rows, 256 threads (4 waves). LDS:
//   pcal[16][128 uint4] 32KB : p bf16 (softmax->gemm1)  then cal bf16 (gemm3->sort)
//   sortbuf[4096 u32]   16KB : h1 bf16 @ shorts[0,2048)    = uint4 [0,256)
//                              h2 bf16 @ shorts[2048,4096) = uint4 [256,512)
//                              (r10 BUG: h2 was written at shorts+4096 while gemm3
//                               read uint4 256 -> uninit LDS -> NaN. Fixed: 2048.)
//                              then per-wave 1024-word sort regions.
// Chunk layout (row r, logical 16B chunk c) stored at chunk index c^(r&7) within the
// row: identical to the proven k_gemm XOR scheme. B operands (W1t/W2t/W3t, 545KB,
// L2-resident) are loaded global->fragment directly. Sort phase: proven v6 counting
// sort per wave, 4 rows sequential, cal from LDS, mx/inv carried in regs from ph 1.
__global__ __launch_bounds__(256) void k_fused(const float* __restrict__ logits,
                                               const unsigned short* __restrict__ W1t,
                                               const float* __restrict__ b1,
                                               const unsigned short* __restrict__ W2t,
                                               const float* __restrict__ b2,
                                               const unsigned short* __restrict__ W3t,
                                               const float* __restrict__ b3,
                                               float* __restrict__ out) {
    __shared__ uint4 pcal[16 * 128];
    __shared__ unsigned int sortbuf[4 * 1024];

    const int tid = threadIdx.x, lane = tid & 63, wv = tid >> 6;
    const int l15 = lane & 15, l4 = lane >> 4;
    const int row0 = blockIdx.x << 4;
    const int base = lane << 4;

    // ---------- phase 1: softmax, wave wv owns rows 4wv..4wv+3 ----------
    float mxs[4], invs[4];
#pragma unroll
    for (int rr = 0; rr < 4; ++rr) {
        const int r = (wv << 2) + rr;
        const float* lrow = logits + (size_t)(row0 + r) * CDIM;
        float lg[16];
#pragma unroll
        for (int q = 0; q < 4; ++q) {
            const int c = base + (q << 2);
            if (c < CDIM) {
                const float4 v4 = *reinterpret_cast<const float4*>(lrow + c);
                lg[q * 4] = v4.x; lg[q * 4 + 1] = v4.y; lg[q * 4 + 2] = v4.z; lg[q * 4 + 3] = v4.w;
            } else {
                lg[q * 4] = lg[q * 4 + 1] = lg[q * 4 + 2] = lg[q * 4 + 3] = -INFINITY;
            }
        }
        float mx = lg[0];
#pragma unroll
        for (int e = 1; e < 16; ++e) mx = fmaxf(mx, lg[e]);
#pragma unroll
        for (int off = 32; off >= 1; off >>= 1) mx = fmaxf(mx, __shfl_xor(mx, off));
        float p[16], s = 0.f;
#pragma unroll
        for (int e = 0; e < 16; ++e) { p[e] = __expf(lg[e] - mx); s += p[e]; }
#pragma unroll
        for (int off = 32; off >= 1; off >>= 1) s += __shfl_xor(s, off);
        const float inv = 1.f / s;
        mxs[rr] = mx; invs[rr] = inv;
        unsigned int w[8];
#pragma unroll
        for (int i = 0; i < 8; ++i) {
            const unsigned int lo = f2bf(p[2 * i] * inv);
            const unsigned int hi = f2bf(p[2 * i + 1] * inv);
            w[i] = lo | (hi << 16);
        }
        uint4 o0, o1;
        o0.x = w[0]; o0.y = w[1]; o0.z = w[2]; o0.w = w[3];
        o1.x = w[4]; o1.y = w[5]; o1.z = w[6]; o1.w = w[7];
        pcal[r * 128 + ((2 * lane) ^ (r & 7))] = o0;
        pcal[r * 128 + ((2 * lane + 1) ^ (r & 7))] = o1;
    }
    __syncthreads();

    // ---------- phase 2: gemm1  h1 = relu(p @ W1 + b1), M=16 N=128 K=1024 ----------
    {
        const int wn = wv << 5;   // 32 cols per wave
        f32x4 acc[2] = {};
#pragma unroll 8
        for (int kk = 0; kk < 32; ++kk) {
            const short8 a = *reinterpret_cast<const short8*>(
                &pcal[l15 * 128 + (((kk << 2) + l4) ^ (l15 & 7))]);
#pragma unroll
            for (int nf = 0; nf < 2; ++nf) {
                const int n = wn + (nf << 4) + l15;
                const short8 b = *reinterpret_cast<const short8*>(
                    W1t + (size_t)n * CPAD + (kk << 5) + (l4 << 3));
                acc[nf] = __builtin_amdgcn_mfma_f32_16x16x32_bf16(a, b, acc[nf], 0, 0, 0);
            }
        }
        unsigned short* h1 = (unsigned short*)sortbuf;   // shorts [0, 2048)
#pragma unroll
        for (int nf = 0; nf < 2; ++nf) {
            const int n = wn + (nf << 4) + l15;
            const float bv = b1[n];
#pragma unroll
            for (int j = 0; j < 4; ++j) {
                const int m = (l4 << 2) + j;
                h1[m * 128 + ((((n >> 3) ^ (m & 7))) << 3) + (n & 7)] =
                    f2bf(fmaxf(acc[nf][j] + bv, 0.f));
            }
        }
    }
    __syncthreads();

    // ---------- phase 3: gemm2  h2 = relu(h1 @ W2 + b2), M=16 N=128 K=128 ----------
    {
        const int wn = wv << 5;
        f32x4 acc[2] = {};
#pragma unroll
        for (int kk = 0; kk < 4; ++kk) {
            const short8 a = *reinterpret_cast<const short8*>(
                &((const uint4*)sortbuf)[l15 * 16 + (((kk << 2) + l4) ^ (l15 & 7))]);
#pragma unroll
            for (int nf = 0; nf < 2; ++nf) {
                const int n = wn + (nf << 4) + l15;
                const short8 b = *reinterpret_cast<const short8*>(
                    W2t + (size_t)n * HDIM + (kk << 5) + (l4 << 3));
                acc[nf] = __builtin_amdgcn_mfma_f32_16x16x32_bf16(a, b, acc[nf], 0, 0, 0);
            }
        }
        unsigned short* h2 = (unsigned short*)sortbuf + 2048;   // shorts [2048,4096) = uint4 [256,512)
#pragma unroll
        for (int nf = 0; nf < 2; ++nf) {
            const int n = wn + (nf << 4) + l15;
            const float bv = b2[n];
#pragma unroll
            for (int j = 0; j < 4; ++j) {
                const int m = (l4 << 2) + j;
                h2[m * 128 + ((((n >> 3) ^ (m & 7))) << 3) + (n & 7)] =
                    f2bf(fmaxf(acc[nf][j] + bv, 0.f));
            }
        }
    }
    __syncthreads();

    // ---------- phase 4: gemm3  cal = epi(h2 @ W3 + b3), M=16 N=1024 K=128 ----------
    {
        f32x4 acc3[16] = {};
#pragma unroll
        for (int kk = 0; kk < 4; ++kk) {
            const short8 a = *reinterpret_cast<const short8*>(
                &((const uint4*)sortbuf)[256 + l15 * 16 + (((kk << 2) + l4) ^ (l15 & 7))]);
#pragma unroll
            for (int nf = 0; nf < 16; ++nf) {
                const int n = (wv << 8) + (nf << 4) + l15;
                const short8 b = *reinterpret_cast<const short8*>(
                    W3t + (size_t)n * HDIM + (kk << 5) + (l4 << 3));
                acc3[nf] = __builtin_amdgcn_mfma_f32_16x16x32_bf16(a, b, acc3[nf], 0, 0, 0);
            }
        }
        unsigned short* calw = (unsigned short*)pcal;
#pragma unroll
        for (int nf = 0; nf < 16; ++nf) {
            const int n = (wv << 8) + (nf << 4) + l15;
            const float bv = (n < CDIM) ? b3[n] : 0.f;
#pragma unroll
            for (int j = 0; j < 4; ++j) {
                const int m = (l4 << 2) + j;
                float v = acc3[nf][j] + bv;
                if (n != CDIM - 1) v = 1.f / (1.f + __expf(-v));
                calw[m * 1024 + (((n >> 3) ^ (m & 7)) << 3) + (n & 7)] = f2bf(v);
            }
        }
    }
    __syncthreads();   // cal complete; h2 reads done -> sortbuf free for sort regions

    // ---------- phase 5: counting sort + finish, wave wv rows 4wv..4wv+3 ----------
    unsigned int* sm = &sortbuf[wv << 10];
    int cb[4];
#pragma unroll
    for (int j = 0; j < 4; ++j) { const int wd = base + (j << 2); cb[j] = SWZ(wd); }

    for (int rr = 0; rr < 4; ++rr) {
        const int r = (wv << 2) + rr;
        const int grow = row0 + r;

        // zero histogram (4 x b128 across the wave)
        {
            uint4 z; z.x = 0; z.y = 0; z.z = 0; z.w = 0;
#pragma unroll
            for (int j = 0; j < 4; ++j) *reinterpret_cast<uint4*>(&sm[cb[j]]) = z;
        }

        // reload logits (L2/L3-warm from phase 1); recompute p with saved stats
        const float* lrow = logits + (size_t)grow * CDIM;
        float lg[16];
#pragma unroll
        for (int q = 0; q < 4; ++q) {
            const int c = base + (q << 2);
            if (c < CDIM) {
                const float4 v4 = *reinterpret_cast<const float4*>(lrow + c);
                lg[q * 4] = v4.x; lg[q * 4 + 1] = v4.y; lg[q * 4 + 2] = v4.z; lg[q * 4 + 3] = v4.w;
            } else {
                lg[q * 4] = lg[q * 4 + 1] = lg[q * 4 + 2] = lg[q * 4 + 3] = -INFINITY;
            }
        }
        // cal row from LDS (chunks 2L, 2L+1 of row r)
        const uint4 c0v = pcal[r * 128 + ((2 * lane) ^ (r & 7))];
        const uint4 c1v = pcal[r * 128 + ((2 * lane + 1) ^ (r & 7))];

        const float mx = mxs[rr], inv = invs[rr];
        float p[16];
#pragma unroll
        for (int e = 0; e < 16; ++e) p[e] = __expf(lg[e] - mx) * inv;

        // single atomic pass: histogram + stable in-bucket offset
        unsigned int offv[16]; int swk[16];
#pragma unroll
        for (int e = 0; e < 16; ++e) {
            const unsigned int key = __float_as_uint(p[e]) >> 20;  // 11-bit monotone
            swk[e] = SWZ((int)key);
            offv[e] = (base + e < CDIM) ? atomicAdd(&sm[swk[e]], 1u) : 0u;
        }

        // bucket suffix-scan
        {
            unsigned int c16[16];
#pragma unroll
            for (int j = 0; j < 4; ++j) {
                const uint4 v4 = *reinterpret_cast<const uint4*>(&sm[cb[j]]);
                c16[4 * j] = v4.x; c16[4 * j + 1] = v4.y; c16[4 * j + 2] = v4.z; c16[4 * j + 3] = v4.w;
            }
            unsigned int lsum = 0;
#pragma unroll
            for (int e = 0; e < 16; ++e) lsum += c16[e];
            unsigned int suf = lsum;
#pragma unroll
            for (int off = 1; off < 64; off <<= 1) {
                const unsigned int u = __shfl_down(suf, off);
                if (lane + off < 64) suf += u;
            }
            unsigned int run = suf - lsum;
            unsigned int stv[16];
#pragma unroll
            for (int e = 15; e >= 0; --e) { stv[e] = run; run += c16[e]; }
#pragma unroll
            for (int j = 0; j < 4; ++j) {
                uint4 v4;
                v4.x = stv[4 * j]; v4.y = stv[4 * j + 1]; v4.z = stv[4 * j + 2]; v4.w = stv[4 * j + 3];
                *reinterpret_cast<uint4*>(&sm[cb[j]]) = v4;
            }
        }

        // rank = start[key] + offset
        int swr[16];
#pragma unroll
        for (int e = 0; e < 16; ++e) {
            const int rk = (base + e < CDIM) ? (int)(sm[swk[e]] + offv[e]) : 1023;
            swr[e] = SWZ(rk);
        }

        // scatter probs to rank order
#pragma unroll
        for (int e = 0; e < 16; ++e)
            if (base + e < CDIM) sm[swr[e]] = __float_as_uint(p[e]);

        // blocked read of sorted probs
        float sp[16];
#pragma unroll
        for (int j = 0; j < 4; ++j) {
            const uint4 v4 = *reinterpret_cast<const uint4*>(&sm[cb[j]]);
            sp[4 * j] = __uint_as_float(v4.x); sp[4 * j + 1] = __uint_as_float(v4.y);
            sp[4 * j + 2] = __uint_as_float(v4.z); sp[4 * j + 3] = __uint_as_float(v4.w);
        }
        const float spn_next = __shfl_down(sp[0], 1);
        const unsigned int cw[8] = {c0v.x, c0v.y, c0v.z, c0v.w, c1v.x, c1v.y, c1v.z, c1v.w};
        float v[16];
#pragma unroll
        for (int e = 0; e < 16; ++e) {
            const int rk = base + e;
            const float cv = bf2f((unsigned short)((cw[e >> 1] >> ((e & 1) * 16)) & 0xFFFFu));
            const float spn = (e < 15) ? sp[e + 1] : spn_next;
            float val;
            if (rk < CDIM - 1) val = (sp[e] - spn) * cv;
            else if (rk == CDIM - 1) val = cv;
            else val = 0.f;
            v[e] = val;
        }
        float lsuf[16], run = 0.f;
#pragma unroll
        for (int e = 15; e >= 0; --e) { run += v[e]; lsuf[e] = run; }
        float pi = run;
#pragma unroll
        for (int off = 1; off < 64; off <<= 1) {
            const float u = __shfl_up(pi, off);
            if (lane >= off) pi += u;
        }
        const float tot = __shfl(pi, 63);
        const float after = tot - pi;

        // S array overwrites sorted probs, gather by rank, add logits, store
#pragma unroll
        for (int j = 0; j < 4; ++j) {
            uint4 v4;
            v4.x = __float_as_uint(lsuf[4 * j] + after);
            v4.y = __float_as_uint(lsuf[4 * j + 1] + after);
            v4.z = __float_as_uint(lsuf[4 * j + 2] + after);
            v4.w = __float_as_uint(lsuf[4 * j + 3] + after);
            *reinterpret_cast<uint4*>(&sm[cb[j]]) = v4;
        }
        float f[16];
#pragma unroll
        for (int e = 0; e < 16; ++e) f[e] = __uint_as_float(sm[swr[e]]);
#pragma unroll
        for (int q = 0; q < 4; ++q) {
            const int c = base + (q << 2);
            if (c < CDIM) {
                float4 o;
                o.x = lg[q * 4] + f[q * 4];
                o.y = lg[q * 4 + 1] + f[q * 4 + 1];
                o.z = lg[q * 4 + 2] + f[q * 4 + 2];
                o.w = lg[q * 4 + 3] + f[q * 4 + 3];
                *reinterpret_cast<float4*>(out + (size_t)grow * CDIM + c) = o;
            }
        }
    }
}

// ---------------- host ----------------
extern "C" void kernel_launch(void* const* d_in, const int* in_sizes, int n_in,
                              void* d_out, int out_size, void* d_ws, size_t ws_size,
                              hipStream_t stream) {
    const float* logits = (const float*)d_in[0];
    const float* W1 = (const float*)d_in[1];
    const float* b1 = (const float*)d_in[2];
    const float* W2 = (const float*)d_in[3];
    const float* b2 = (const float*)d_in[4];
    const float* W3 = (const float*)d_in[5];
    const float* b3 = (const float*)d_in[6];
    float* out = (float*)d_out;

    char* ws = (char*)d_ws;
    unsigned short* W1t = (unsigned short*)ws;             // 256 KB
    unsigned short* W2t = (unsigned short*)(ws + 262144);  // 32 KB
    unsigned short* W3t = (unsigned short*)(ws + 294912);  // 256 KB

    k_prep<<<512, 256, 0, stream>>>(W1, W2, W3, W1t, W2t, W3t);
    k_fused<<<BROWS / 16, 256, 0, stream>>>(logits, W1t, b1, W2t, b2, W3t, b3, out);
}